// Round 4
// baseline (61.096 us; speedup 1.0000x reference)
//
#include <hip/hip_runtime.h>
#include <math.h>

#define NPTS 8192
#define MPTS 8192
#define LATENT 64
#define TI 32          // rows per block tile
#define BLK 256        // threads per block
#define COLS_PER_T 4   // columns per thread (float4 store)

typedef float f32x4 __attribute__((ext_vector_type(4)));

// ---------------------------------------------------------------------------
// Kernel 1: per-point lengthscale MLP
//   s(p) = softplus( W2 @ selu(W1 @ p + b1) + b2 )
// One thread per point; x points first, then y points, into s_all[N+M].
// ---------------------------------------------------------------------------
__global__ __launch_bounds__(256)
void nsm_scale_kernel(const float* __restrict__ x,
                      const float* __restrict__ y,
                      const float* __restrict__ W1,
                      const float* __restrict__ b1,
                      const float* __restrict__ W2,
                      const float* __restrict__ b2,
                      float* __restrict__ s_all) {
    int i = blockIdx.x * blockDim.x + threadIdx.x;
    if (i >= NPTS + MPTS) return;
    const float* p = (i < NPTS) ? (x + 3 * i) : (y + 3 * (i - NPTS));
    float p0 = p[0], p1 = p[1], p2 = p[2];

    const float kScale = 1.0507009873554805f;   // selu scale
    const float kAlpha = 1.6732632423543772f;   // selu alpha

    float acc = b2[0];
#pragma unroll 16
    for (int l = 0; l < LATENT; ++l) {
        float h = b1[l];
        h = fmaf(W1[3 * l + 0], p0, h);
        h = fmaf(W1[3 * l + 1], p1, h);
        h = fmaf(W1[3 * l + 2], p2, h);
        float sh = (h > 0.0f) ? (kScale * h)
                              : (kScale * kAlpha * (__expf(h) - 1.0f));
        acc = fmaf(W2[l], sh, acc);
    }
    // numerically-stable softplus: log1p(exp(-|x|)) + max(x,0)
    float sp = fmaxf(acc, 0.0f) + log1pf(__expf(-fabsf(acc)));
    s_all[i] = sp;
}

// ---------------------------------------------------------------------------
// Kernel 2: fused pairwise Matern-5/2 tile kernel.
// Block tile: TI rows x (BLK*4) cols. Each thread: 4 consecutive columns.
// Rows (x-point coords + sx + ||x||^2) staged in LDS, broadcast-read.
// Output: one regular coalesced float4 per thread per row (through L2 —
// NT bypass measured as the suspect for the 5.2 vs 7.0 TB/s write gap).
// ---------------------------------------------------------------------------
__global__ __launch_bounds__(BLK, 8)
void nsm_matern_kernel(const float* __restrict__ x,
                       const float* __restrict__ y,
                       const float* __restrict__ s_all,
                       float* __restrict__ out) {
    __shared__ float4 lx[TI];   // (x0, x1, x2, sx)
    __shared__ float  lxx[TI];  // ||x||^2

    const int rowBase = blockIdx.y * TI;
    const int colBase = blockIdx.x * (BLK * COLS_PER_T) + threadIdx.x * COLS_PER_T;

    // ---- stage TI rows into LDS ----
    if (threadIdx.x < TI) {
        int r = rowBase + threadIdx.x;
        float a0 = x[3 * r + 0];
        float a1 = x[3 * r + 1];
        float a2 = x[3 * r + 2];
        lx[threadIdx.x]  = make_float4(a0, a1, a2, s_all[r]);
        lxx[threadIdx.x] = fmaf(a0, a0, fmaf(a1, a1, a2 * a2));
    }

    // ---- per-thread column data: 4 columns = 12 consecutive floats, aligned ----
    const float4* yp = reinterpret_cast<const float4*>(y + 3 * colBase);
    float4 q0 = yp[0];
    float4 q1 = yp[1];
    float4 q2 = yp[2];
    float cy[COLS_PER_T][3] = {
        {q0.x, q0.y, q0.z},
        {q0.w, q1.x, q1.y},
        {q1.z, q1.w, q2.x},
        {q2.y, q2.z, q2.w},
    };
    float4 s4 = *reinterpret_cast<const float4*>(s_all + NPTS + colBase);
    float syA[COLS_PER_T] = {s4.x, s4.y, s4.z, s4.w};
    float yyA[COLS_PER_T];
#pragma unroll
    for (int c = 0; c < COLS_PER_T; ++c) {
        yyA[c] = fmaf(cy[c][0], cy[c][0],
                 fmaf(cy[c][1], cy[c][1], cy[c][2] * cy[c][2]));
    }

    __syncthreads();

    const float sq5 = 2.2360679774997896f;     // sqrt(5)
    const float c53 = 5.0f / 3.0f;
    const float cE  = -3.2262751842f;          // -sqrt(5)*log2(e): exp(-t)=exp2(cE*rs)

    f32x4* outp = reinterpret_cast<f32x4*>(out) +
                  (size_t)rowBase * (MPTS / 4) + (colBase / 4);

#pragma unroll 4
    for (int r = 0; r < TI; ++r) {
        float4 xv = lx[r];       // broadcast (all lanes same addr -> no conflict)
        float  xx = lxx[r];
        float  res[COLS_PER_T];
#pragma unroll
        for (int c = 0; c < COLS_PER_T; ++c) {
            float dot = fmaf(xv.x, cy[c][0],
                        fmaf(xv.y, cy[c][1], xv.z * cy[c][2]));
            float r2  = fmaf(-2.0f, dot, xx + yyA[c]);
            // raw v_sqrt_f32 (~1.5 ulp); threshold is 2e-2, this is noise.
            float rr  = __builtin_amdgcn_sqrtf(fmaxf(r2, 1e-12f));
            float rs  = rr * (xv.w + syA[c]);
            float t   = sq5 * rs;
            float poly = fmaf(c53 * rs, rs, 1.0f + t);
            float e   = __builtin_amdgcn_exp2f(cE * rs);   // exp(-sqrt5*rs)
            res[c] = poly * e;
        }
        *outp = f32x4{res[0], res[1], res[2], res[3]};
        outp += MPTS / 4;  // next row
    }
}

// ---------------------------------------------------------------------------
extern "C" void kernel_launch(void* const* d_in, const int* in_sizes, int n_in,
                              void* d_out, int out_size, void* d_ws, size_t ws_size,
                              hipStream_t stream) {
    const float* x  = (const float*)d_in[0];
    const float* y  = (const float*)d_in[1];
    const float* W1 = (const float*)d_in[2];
    const float* b1 = (const float*)d_in[3];
    const float* W2 = (const float*)d_in[4];
    const float* b2 = (const float*)d_in[5];
    float* out   = (float*)d_out;
    float* s_all = (float*)d_ws;   // (NPTS + MPTS) floats = 64 KB

    // Kernel 1: per-point scales
    {
        int total = NPTS + MPTS;
        int blocks = (total + 255) / 256;
        nsm_scale_kernel<<<blocks, 256, 0, stream>>>(x, y, W1, b1, W2, b2, s_all);
    }

    // Kernel 2: fused pairwise kernel matrix
    {
        dim3 grid(MPTS / (BLK * COLS_PER_T), NPTS / TI);  // (8, 256)
        dim3 block(BLK);
        nsm_matern_kernel<<<grid, block, 0, stream>>>(x, y, s_all, out);
    }
}

// Round 5
// 56.993 us; speedup vs baseline: 1.0720x; 1.0720x over previous
//
#include <hip/hip_runtime.h>
#include <math.h>

#define NPTS 8192
#define MPTS 8192
#define LATENT 64
#define TI 32          // rows per block tile
#define BLK 256        // threads per block
#define COLS_PER_T 4   // columns per thread (float4 store)

typedef float f32x4 __attribute__((ext_vector_type(4)));

// ---------------------------------------------------------------------------
// Kernel 1: per-point lengthscale MLP
//   s(p) = softplus( W2 @ selu(W1 @ p + b1) + b2 )
// One thread per point; x points first, then y points, into s_all[N+M].
// ---------------------------------------------------------------------------
__global__ __launch_bounds__(256)
void nsm_scale_kernel(const float* __restrict__ x,
                      const float* __restrict__ y,
                      const float* __restrict__ W1,
                      const float* __restrict__ b1,
                      const float* __restrict__ W2,
                      const float* __restrict__ b2,
                      float* __restrict__ s_all) {
    int i = blockIdx.x * blockDim.x + threadIdx.x;
    if (i >= NPTS + MPTS) return;
    const float* p = (i < NPTS) ? (x + 3 * i) : (y + 3 * (i - NPTS));
    float p0 = p[0], p1 = p[1], p2 = p[2];

    const float kScale = 1.0507009873554805f;   // selu scale
    const float kAlpha = 1.6732632423543772f;   // selu alpha

    float acc = b2[0];
#pragma unroll 16
    for (int l = 0; l < LATENT; ++l) {
        float h = b1[l];
        h = fmaf(W1[3 * l + 0], p0, h);
        h = fmaf(W1[3 * l + 1], p1, h);
        h = fmaf(W1[3 * l + 2], p2, h);
        float sh = (h > 0.0f) ? (kScale * h)
                              : (kScale * kAlpha * (__expf(h) - 1.0f));
        acc = fmaf(W2[l], sh, acc);
    }
    // numerically-stable softplus: log1p(exp(-|x|)) + max(x,0)
    float sp = fmaxf(acc, 0.0f) + log1pf(__expf(-fabsf(acc)));
    s_all[i] = sp;
}

// ---------------------------------------------------------------------------
// Kernel 2: fused pairwise Matern-5/2 tile kernel.
// Block tile: TI rows x (BLK*4) cols. Each thread: 4 consecutive columns.
// Rows (x-point coords + sx + ||x||^2) staged in LDS, broadcast-read.
// Output: one NONTEMPORAL float4 per thread per row. Measured: NT stores
// are +3.5us vs regular (round 3: 57.6us NT vs round 4: 61.1us regular) —
// write-once stream, keep it out of L2.
// ---------------------------------------------------------------------------
__global__ __launch_bounds__(BLK)
void nsm_matern_kernel(const float* __restrict__ x,
                       const float* __restrict__ y,
                       const float* __restrict__ s_all,
                       float* __restrict__ out) {
    __shared__ float4 lx[TI];   // (x0, x1, x2, sx)
    __shared__ float  lxx[TI];  // ||x||^2

    const int rowBase = blockIdx.y * TI;
    const int colBase = blockIdx.x * (BLK * COLS_PER_T) + threadIdx.x * COLS_PER_T;

    // ---- stage TI rows into LDS ----
    if (threadIdx.x < TI) {
        int r = rowBase + threadIdx.x;
        float a0 = x[3 * r + 0];
        float a1 = x[3 * r + 1];
        float a2 = x[3 * r + 2];
        lx[threadIdx.x]  = make_float4(a0, a1, a2, s_all[r]);
        lxx[threadIdx.x] = fmaf(a0, a0, fmaf(a1, a1, a2 * a2));
    }

    // ---- per-thread column data: 4 columns = 12 consecutive floats, aligned ----
    const float4* yp = reinterpret_cast<const float4*>(y + 3 * colBase);
    float4 q0 = yp[0];
    float4 q1 = yp[1];
    float4 q2 = yp[2];
    float cy[COLS_PER_T][3] = {
        {q0.x, q0.y, q0.z},
        {q0.w, q1.x, q1.y},
        {q1.z, q1.w, q2.x},
        {q2.y, q2.z, q2.w},
    };
    float4 s4 = *reinterpret_cast<const float4*>(s_all + NPTS + colBase);
    float syA[COLS_PER_T] = {s4.x, s4.y, s4.z, s4.w};
    float yyA[COLS_PER_T];
#pragma unroll
    for (int c = 0; c < COLS_PER_T; ++c) {
        yyA[c] = fmaf(cy[c][0], cy[c][0],
                 fmaf(cy[c][1], cy[c][1], cy[c][2] * cy[c][2]));
    }

    __syncthreads();

    const float sq5 = 2.2360679774997896f;     // sqrt(5)
    const float c53 = 5.0f / 3.0f;
    const float cE  = -3.2262751842f;          // -sqrt(5)*log2(e): exp(-sq5*u)=exp2(cE*u)

    f32x4* outp = reinterpret_cast<f32x4*>(out) +
                  (size_t)rowBase * (MPTS / 4) + (colBase / 4);

#pragma unroll 4
    for (int r = 0; r < TI; ++r) {
        float4 xv = lx[r];       // broadcast (all lanes same addr -> no conflict)
        float  xx = lxx[r];
        float  res[COLS_PER_T];
#pragma unroll
        for (int c = 0; c < COLS_PER_T; ++c) {
            float dot = fmaf(xv.x, cy[c][0],
                        fmaf(xv.y, cy[c][1], xv.z * cy[c][2]));
            float r2  = fmaf(-2.0f, dot, xx + yyA[c]);
            // raw v_sqrt_f32 (~1.5 ulp); threshold is 2e-2, this is noise.
            float u   = __builtin_amdgcn_sqrtf(fmaxf(r2, 1e-12f))
                        * (xv.w + syA[c]);                  // u = r * (sx+sy)
            // poly = 1 + sqrt5*u + (5/3)*u^2, Horner: 2 FMAs
            float poly = fmaf(fmaf(c53, u, sq5), u, 1.0f);
            float e    = __builtin_amdgcn_exp2f(cE * u);    // exp(-sqrt5*u)
            res[c] = poly * e;
        }
        f32x4 v = {res[0], res[1], res[2], res[3]};
        __builtin_nontemporal_store(v, outp);
        outp += MPTS / 4;  // next row
    }
}

// ---------------------------------------------------------------------------
extern "C" void kernel_launch(void* const* d_in, const int* in_sizes, int n_in,
                              void* d_out, int out_size, void* d_ws, size_t ws_size,
                              hipStream_t stream) {
    const float* x  = (const float*)d_in[0];
    const float* y  = (const float*)d_in[1];
    const float* W1 = (const float*)d_in[2];
    const float* b1 = (const float*)d_in[3];
    const float* W2 = (const float*)d_in[4];
    const float* b2 = (const float*)d_in[5];
    float* out   = (float*)d_out;
    float* s_all = (float*)d_ws;   // (NPTS + MPTS) floats = 64 KB

    // Kernel 1: per-point scales
    {
        int total = NPTS + MPTS;
        int blocks = (total + 255) / 256;
        nsm_scale_kernel<<<blocks, 256, 0, stream>>>(x, y, W1, b1, W2, b2, s_all);
    }

    // Kernel 2: fused pairwise kernel matrix
    {
        dim3 grid(MPTS / (BLK * COLS_PER_T), NPTS / TI);  // (8, 256)
        dim3 block(BLK);
        nsm_matern_kernel<<<grid, block, 0, stream>>>(x, y, s_all, out);
    }
}